// Round 3
// baseline (1196.815 us; speedup 1.0000x reference)
//
#include <hip/hip_runtime.h>
#include <math.h>

#define B_ 2
#define S_ 2048
#define HD 2048
#define NH_ 16
#define DH_ 128
#define FF_ 8192
#define MROWS (B_*S_)   // 4096

typedef __attribute__((ext_vector_type(8))) short bf16x8;
typedef __attribute__((ext_vector_type(4))) short s16x4;
typedef __attribute__((ext_vector_type(4))) float f32x4;

static __device__ __forceinline__ unsigned short f2bf(float f) {
    unsigned u = __float_as_uint(f);
    u += 0x7fffu + ((u >> 16) & 1u);   // round-to-nearest-even
    return (unsigned short)(u >> 16);
}

static __device__ __forceinline__ void gload_lds16(const void* g, void* lds) {
    __builtin_amdgcn_global_load_lds((const __attribute__((address_space(1))) void*)g,
                                     (__attribute__((address_space(3))) void*)lds, 16, 0, 0);
}

// ---------------- weight fp32 -> bf16 transpose: Wt[N][K] = bf16(W[K][N]) ----------------
__global__ __launch_bounds__(256) void trcvt_kernel(const float* __restrict__ W,
        short* __restrict__ Wt, int K, int N) {
    __shared__ float tile[32][33];
    int t = threadIdx.x;
    int tx = t & 31, ty = t >> 5;      // ty 0..7
    int r0 = blockIdx.y * 32, c0 = blockIdx.x * 32;
    #pragma unroll
    for (int i = 0; i < 4; i++)
        tile[ty + 8*i][tx] = W[(size_t)(r0 + ty + 8*i) * N + c0 + tx];
    __syncthreads();
    #pragma unroll
    for (int i = 0; i < 4; i++)
        Wt[(size_t)(c0 + ty + 8*i) * K + r0 + tx] = (short)f2bf(tile[tx][ty + 8*i]);
}

// ---------------- LayerNorm fp32 in -> bf16 out ----------------
__global__ __launch_bounds__(256) void ln_kernel(const float* __restrict__ x,
                const float* __restrict__ g, const float* __restrict__ b,
                short* __restrict__ out) {
    int row = blockIdx.x;
    const float* xr = x + (size_t)row * HD;
    short* orow = out + (size_t)row * HD;
    int t = threadIdx.x;

    float4 v0 = ((const float4*)xr)[t];
    float4 v1 = ((const float4*)xr)[t + 256];
    float s  = v0.x + v0.y + v0.z + v0.w + v1.x + v1.y + v1.z + v1.w;
    float ss = v0.x*v0.x + v0.y*v0.y + v0.z*v0.z + v0.w*v0.w
             + v1.x*v1.x + v1.y*v1.y + v1.z*v1.z + v1.w*v1.w;

    #pragma unroll
    for (int off = 1; off < 64; off <<= 1) {
        s  += __shfl_xor(s,  off, 64);
        ss += __shfl_xor(ss, off, 64);
    }
    __shared__ float ws_s[4], ws_q[4];
    int wid = t >> 6;
    if ((t & 63) == 0) { ws_s[wid] = s; ws_q[wid] = ss; }
    __syncthreads();
    s  = ws_s[0] + ws_s[1] + ws_s[2] + ws_s[3];
    ss = ws_q[0] + ws_q[1] + ws_q[2] + ws_q[3];

    float mu  = s * (1.0f / HD);
    float var = ss * (1.0f / HD) - mu * mu;
    float rs  = rsqrtf(var + 1e-5f);

    float4 g0 = ((const float4*)g)[t];
    float4 g1 = ((const float4*)g)[t + 256];
    float4 b0 = ((const float4*)b)[t];
    float4 b1 = ((const float4*)b)[t + 256];
    s16x4 o0, o1;
    o0.x = (short)f2bf((v0.x - mu) * rs * g0.x + b0.x);
    o0.y = (short)f2bf((v0.y - mu) * rs * g0.y + b0.y);
    o0.z = (short)f2bf((v0.z - mu) * rs * g0.z + b0.z);
    o0.w = (short)f2bf((v0.w - mu) * rs * g0.w + b0.w);
    o1.x = (short)f2bf((v1.x - mu) * rs * g1.x + b1.x);
    o1.y = (short)f2bf((v1.y - mu) * rs * g1.y + b1.y);
    o1.z = (short)f2bf((v1.z - mu) * rs * g1.z + b1.z);
    o1.w = (short)f2bf((v1.w - mu) * rs * g1.w + b1.w);
    ((s16x4*)orow)[t]       = o0;
    ((s16x4*)orow)[t + 256] = o1;
}

// ---------------- bf16 MFMA GEMM (m97 structure): C = epi(A @ Bt^T) ----------------
// A [M][K] bf16 row-major, Bt [N][K] bf16 row-major. 128x128 tile, BK=64,
// 4 waves (2x2), each wave 64x64 out = 4x4 MFMA 16x16x32 frags.
template<bool OUTBF16, bool BIAS, bool RES, bool GELU>
__global__ __launch_bounds__(256) void gemm_bf16(
        const short* __restrict__ A, const short* __restrict__ Bt,
        const float* __restrict__ bias, const float* __restrict__ res,
        void* __restrict__ Cout, int M, int N, int K) {
    __shared__ __align__(16) short As[128*64];
    __shared__ __align__(16) short Bs[128*64];
    int t = threadIdx.x;
    int wave = t >> 6, lane = t & 63;
    int l4 = lane >> 4, lm = lane & 15;
    int wr = wave >> 1, wc = wave & 1;
    int m0 = blockIdx.y * 128, n0 = blockIdx.x * 128;

    f32x4 acc[4][4];
    #pragma unroll
    for (int i = 0; i < 4; i++)
        #pragma unroll
        for (int j = 0; j < 4; j++) acc[i][j] = (f32x4){0.f, 0.f, 0.f, 0.f};

    const char* Ab = (const char*)A;
    const char* Bb = (const char*)Bt;

    for (int k0 = 0; k0 < K; k0 += 64) {
        // stage A-tile [128][64] + Bt-tile [128][64], linear LDS, 16B chunks
        #pragma unroll
        for (int L = 0; L < 4; L++) {
            int c   = (wave*4 + L) * 64 + lane;   // chunk 0..1023
            int row = c >> 3;
            gload_lds16(Ab + ((size_t)(m0 + row) * K + k0) * 2 + (c & 7) * 16,
                        (char*)As + (wave*4 + L) * 1024);
            gload_lds16(Bb + ((size_t)(n0 + row) * K + k0) * 2 + (c & 7) * 16,
                        (char*)Bs + (wave*4 + L) * 1024);
        }
        __syncthreads();
        #pragma unroll
        for (int kk = 0; kk < 2; kk++) {
            bf16x8 a[4], b[4];
            #pragma unroll
            for (int m = 0; m < 4; m++) {
                int row = wr*64 + m*16 + lm;
                a[m] = *(const bf16x8*)((const char*)As + row*128 + kk*64 + l4*16);
            }
            #pragma unroll
            for (int n = 0; n < 4; n++) {
                int row = wc*64 + n*16 + lm;
                b[n] = *(const bf16x8*)((const char*)Bs + row*128 + kk*64 + l4*16);
            }
            #pragma unroll
            for (int m = 0; m < 4; m++)
                #pragma unroll
                for (int n = 0; n < 4; n++)
                    acc[m][n] = __builtin_amdgcn_mfma_f32_16x16x32_bf16(a[m], b[n], acc[m][n], 0, 0, 0);
        }
        __syncthreads();
    }

    #pragma unroll
    for (int n = 0; n < 4; n++) {
        int colb = n0 + wc*64 + n*16 + lm;
        float bv = BIAS ? bias[colb] : 0.f;
        #pragma unroll
        for (int m = 0; m < 4; m++) {
            #pragma unroll
            for (int r = 0; r < 4; r++) {
                int row = m0 + wr*64 + m*16 + l4*4 + r;
                float v = acc[m][n][r] + bv;
                if (GELU) v = 0.5f * v * (1.0f + erff(v * 0.70710678118654752f));
                size_t off = (size_t)row * N + colb;
                if (RES) v += res[off];
                if (OUTBF16) ((short*)Cout)[off] = (short)f2bf(v);
                else         ((float*)Cout)[off] = v;
            }
        }
    }
}

// ---------------- MFMA flash attention ----------------
// block = 256 thr = 4 waves; 64 q-rows/block (16/wave); KV tiles of 64.
__global__ __launch_bounds__(256) void attn_kernel(
        const short* __restrict__ qg, const short* __restrict__ kg,
        const short* __restrict__ vg, const float* __restrict__ mask,
        short* __restrict__ ctx) {
    __shared__ __align__(16) short Qs[64*128];      // swizzled row-major
    __shared__ __align__(16) short Ks[64*128];      // swizzled row-major
    __shared__ __align__(16) short Vt[128*64];      // V^T [d][kv], swizzled
    __shared__ __align__(16) short Ps[4][16*64];    // per-wave P, swizzled
    int t = threadIdx.x;
    int wave = t >> 6, lane = t & 63;
    int l4 = lane >> 4, lm = lane & 15;
    int qt = blockIdx.x, h = blockIdx.y, zb = blockIdx.z;
    int q0 = qt * 64;
    const float scale = 0.08838834764831845f;  // 1/sqrt(128)

    // stage Q once (bf16, swizzled)
    #pragma unroll
    for (int p = 0; p < 4; p++) {
        int idx = t + p*256;
        int row = idx >> 4, c8 = idx & 15;
        bf16x8 v = *(const bf16x8*)(qg + (size_t)(zb*S_ + q0 + row) * HD + h*DH_ + c8*8);
        *(bf16x8*)((char*)Qs + ((row*256 + c8*16) ^ ((row & 7) << 4))) = v;
    }

    float m_r[4], l_r[4];
    #pragma unroll
    for (int r = 0; r < 4; r++) { m_r[r] = -INFINITY; l_r[r] = 0.f; }
    f32x4 o[8];
    #pragma unroll
    for (int i = 0; i < 8; i++) o[i] = (f32x4){0.f, 0.f, 0.f, 0.f};

    for (int kv0 = 0; kv0 < S_; kv0 += 64) {
        __syncthreads();   // prior reads done before restaging
        #pragma unroll
        for (int p = 0; p < 4; p++) {
            int idx = t + p*256;
            int row = idx >> 4, c8 = idx & 15;
            size_t goff = (size_t)(zb*S_ + kv0 + row) * HD + h*DH_ + c8*8;
            bf16x8 kvv = *(const bf16x8*)(kg + goff);
            *(bf16x8*)((char*)Ks + ((row*256 + c8*16) ^ ((row & 7) << 4))) = kvv;
            bf16x8 vv = *(const bf16x8*)(vg + goff);
            #pragma unroll
            for (int i = 0; i < 8; i++) {
                int d = c8*8 + i;                      // d&7 == i
                *(short*)((char*)Vt + ((d*128 + row*2) ^ (i << 4))) = vv[i];
            }
        }
        __syncthreads();

        // ---- QK^T: wave's 16 q-rows x 64 kv-cols ----
        f32x4 s[4];
        #pragma unroll
        for (int nb = 0; nb < 4; nb++) s[nb] = (f32x4){0.f, 0.f, 0.f, 0.f};
        bf16x8 aq[4];
        #pragma unroll
        for (int ks = 0; ks < 4; ks++) {
            int row = wave*16 + lm;
            aq[ks] = *(const bf16x8*)((const char*)Qs + ((row*256 + ks*64 + l4*16) ^ ((row & 7) << 4)));
        }
        #pragma unroll
        for (int nb = 0; nb < 4; nb++) {
            int row = nb*16 + lm;
            #pragma unroll
            for (int ks = 0; ks < 4; ks++) {
                bf16x8 bk = *(const bf16x8*)((const char*)Ks + ((row*256 + ks*64 + l4*16) ^ ((row & 7) << 4)));
                s[nb] = __builtin_amdgcn_mfma_f32_16x16x32_bf16(aq[ks], bk, s[nb], 0, 0, 0);
            }
        }

        // ---- online softmax (rows = l4*4+r, cols = lm+16nb; 16-lane row groups) ----
        float mk[4];
        #pragma unroll
        for (int nb = 0; nb < 4; nb++) mk[nb] = mask[(size_t)zb*S_ + kv0 + nb*16 + lm];

        float pv_[4][4], fac[4];
        #pragma unroll
        for (int r = 0; r < 4; r++) {
            float vmax = -INFINITY;
            #pragma unroll
            for (int nb = 0; nb < 4; nb++) {
                float v = s[nb][r] * scale + mk[nb];
                pv_[r][nb] = v;
                vmax = fmaxf(vmax, v);
            }
            vmax = fmaxf(vmax, __shfl_xor(vmax, 1, 64));
            vmax = fmaxf(vmax, __shfl_xor(vmax, 2, 64));
            vmax = fmaxf(vmax, __shfl_xor(vmax, 4, 64));
            vmax = fmaxf(vmax, __shfl_xor(vmax, 8, 64));
            float nm = fmaxf(m_r[r], vmax);
            fac[r] = __expf(m_r[r] - nm);
            float ps = 0.f;
            #pragma unroll
            for (int nb = 0; nb < 4; nb++) {
                float e = __expf(pv_[r][nb] - nm);
                pv_[r][nb] = e;
                ps += e;
            }
            ps += __shfl_xor(ps, 1, 64);
            ps += __shfl_xor(ps, 2, 64);
            ps += __shfl_xor(ps, 4, 64);
            ps += __shfl_xor(ps, 8, 64);
            l_r[r] = l_r[r] * fac[r] + ps;
            m_r[r] = nm;
        }
        #pragma unroll
        for (int i = 0; i < 8; i++)
            #pragma unroll
            for (int r = 0; r < 4; r++) o[i][r] *= fac[r];

        // ---- P -> per-wave LDS (bf16, A-frag layout) ----
        char* Pw = (char*)Ps[wave];
        #pragma unroll
        for (int r = 0; r < 4; r++) {
            int row = l4*4 + r;
            #pragma unroll
            for (int nb = 0; nb < 4; nb++) {
                int col = nb*16 + lm;
                *(short*)(Pw + ((row*128 + col*2) ^ ((row & 7) << 4))) = (short)f2bf(pv_[r][nb]);
            }
        }

        // ---- PV: ctx[16 q][128 d] += P[16][64] @ V[64][128] ----
        #pragma unroll
        for (int ks = 0; ks < 2; ks++) {
            bf16x8 ap = *(const bf16x8*)(Pw + ((lm*128 + ks*64 + l4*16) ^ ((lm & 7) << 4)));
            #pragma unroll
            for (int nd = 0; nd < 8; nd++) {
                int d = nd*16 + lm;                    // d&7 == lm&7
                bf16x8 bv = *(const bf16x8*)((const char*)Vt + ((d*128 + ks*64 + l4*16) ^ ((lm & 7) << 4)));
                o[nd] = __builtin_amdgcn_mfma_f32_16x16x32_bf16(ap, bv, o[nd], 0, 0, 0);
            }
        }
    }

    #pragma unroll
    for (int nd = 0; nd < 8; nd++) {
        #pragma unroll
        for (int r = 0; r < 4; r++) {
            float v = o[nd][r] / l_r[r];
            size_t row = (size_t)(zb*S_ + q0 + wave*16 + l4*4 + r);
            ctx[row * HD + h*DH_ + nd*16 + lm] = (short)f2bf(v);
        }
    }
}

extern "C" void kernel_launch(void* const* d_in, const int* in_sizes, int n_in,
                              void* d_out, int out_size, void* d_ws, size_t ws_size,
                              hipStream_t stream) {
    const float* x      = (const float*)d_in[0];
    const float* mask   = (const float*)d_in[1];
    const float* ln1_g  = (const float*)d_in[2];
    const float* ln1_b  = (const float*)d_in[3];
    const float* ln2_g  = (const float*)d_in[4];
    const float* ln2_b  = (const float*)d_in[5];
    const float* Wq     = (const float*)d_in[6];
    const float* Wk     = (const float*)d_in[7];
    const float* Wv     = (const float*)d_in[8];
    const float* Wo     = (const float*)d_in[9];
    const float* W1     = (const float*)d_in[10];
    const float* b1     = (const float*)d_in[11];
    const float* W2     = (const float*)d_in[12];
    const float* b2     = (const float*)d_in[13];
    float* out = (float*)d_out;

    char* ws = (char*)d_ws;
    size_t off = 0;
    const size_t WSQ = (size_t)HD * HD * 2;        // 8,388,608 B
    const size_t WFF = (size_t)HD * FF_ * 2;       // 33,554,432 B
    const size_t ACT = (size_t)MROWS * HD * 2;     // 16,777,216 B
    short* WqT = (short*)(ws + off); off += WSQ;
    short* WkT = (short*)(ws + off); off += WSQ;
    short* WvT = (short*)(ws + off); off += WSQ;
    short* WoT = (short*)(ws + off); off += WSQ;
    short* W1T = (short*)(ws + off); off += WFF;
    short* W2T = (short*)(ws + off); off += WFF;
    short* hb  = (short*)(ws + off); off += ACT;   // LN1 out, later LN2 out
    short* qb  = (short*)(ws + off); off += ACT;
    short* kb  = (short*)(ws + off); off += ACT;
    short* vb  = (short*)(ws + off); off += ACT;
    short* cb  = (short*)(ws + off); off += ACT;
    float* x1  = (float*)(ws + off); off += (size_t)MROWS * HD * 4;
    short* act = qb;   // overlay: qb..cb region (67.1 MB) holds 4096x8192 bf16

    dim3 blk(256);

    // weight convert+transpose (bf16, [N][K])
    trcvt_kernel<<<dim3(HD/32,  HD/32),  blk, 0, stream>>>(Wq, WqT, HD, HD);
    trcvt_kernel<<<dim3(HD/32,  HD/32),  blk, 0, stream>>>(Wk, WkT, HD, HD);
    trcvt_kernel<<<dim3(HD/32,  HD/32),  blk, 0, stream>>>(Wv, WvT, HD, HD);
    trcvt_kernel<<<dim3(HD/32,  HD/32),  blk, 0, stream>>>(Wo, WoT, HD, HD);
    trcvt_kernel<<<dim3(FF_/32, HD/32),  blk, 0, stream>>>(W1, W1T, HD, FF_);
    trcvt_kernel<<<dim3(HD/32,  FF_/32), blk, 0, stream>>>(W2, W2T, FF_, HD);

    // 1) h = LN1(x) -> bf16
    ln_kernel<<<MROWS, blk, 0, stream>>>(x, ln1_g, ln1_b, hb);

    // 2) q,k,v
    dim3 gqkv(HD/128, MROWS/128);
    gemm_bf16<true,false,false,false><<<gqkv, blk, 0, stream>>>(hb, WqT, nullptr, nullptr, qb, MROWS, HD, HD);
    gemm_bf16<true,false,false,false><<<gqkv, blk, 0, stream>>>(hb, WkT, nullptr, nullptr, kb, MROWS, HD, HD);
    gemm_bf16<true,false,false,false><<<gqkv, blk, 0, stream>>>(hb, WvT, nullptr, nullptr, vb, MROWS, HD, HD);

    // 3) ctx = softmax(qk^T*scale + mask) v  -> bf16
    attn_kernel<<<dim3(S_/64, NH_, B_), blk, 0, stream>>>(qb, kb, vb, mask, cb);

    // 4) x1 = x + ctx @ Wo  (f32)
    gemm_bf16<false,false,true,false><<<gqkv, blk, 0, stream>>>(cb, WoT, nullptr, x, x1, MROWS, HD, HD);

    // 5) h2 = LN2(x1) -> bf16 (reuse hb)
    ln_kernel<<<MROWS, blk, 0, stream>>>(x1, ln2_g, ln2_b, hb);

    // 6) act = gelu(h2 @ W1 + b1) -> bf16 (overlays q/k/v/ctx)
    gemm_bf16<true,true,false,true><<<dim3(FF_/128, MROWS/128), blk, 0, stream>>>(hb, W1T, b1, nullptr, act, MROWS, FF_, HD);

    // 7) out = x1 + act @ W2 + b2  (f32)
    gemm_bf16<false,true,true,false><<<gqkv, blk, 0, stream>>>(act, W2T, b2, x1, out, MROWS, HD, FF_);
}

// Round 4
// 1049.847 us; speedup vs baseline: 1.1400x; 1.1400x over previous
//
#include <hip/hip_runtime.h>
#include <math.h>

#define B_ 2
#define S_ 2048
#define HD 2048
#define NH_ 16
#define DH_ 128
#define FF_ 8192
#define MROWS (B_*S_)   // 4096
#define LDQ 6144        // fused qkv row stride

typedef __attribute__((ext_vector_type(8))) short bf16x8;
typedef __attribute__((ext_vector_type(4))) short s16x4;
typedef __attribute__((ext_vector_type(4))) float f32x4;

static __device__ __forceinline__ unsigned short f2bf(float f) {
    unsigned u = __float_as_uint(f);
    u += 0x7fffu + ((u >> 16) & 1u);   // round-to-nearest-even
    return (unsigned short)(u >> 16);
}

static __device__ __forceinline__ void gload_lds16(const void* g, void* lds) {
    __builtin_amdgcn_global_load_lds((const __attribute__((address_space(1))) void*)g,
                                     (__attribute__((address_space(3))) void*)lds, 16, 0, 0);
}

// ---------------- weight fp32 -> bf16 transpose: Wt[N][K] = bf16(W[K][N]) ----------------
__global__ __launch_bounds__(256) void trcvt_kernel(const float* __restrict__ W,
        short* __restrict__ Wt, int K, int N) {
    __shared__ float tile[32][33];
    int t = threadIdx.x;
    int tx = t & 31, ty = t >> 5;      // ty 0..7
    int r0 = blockIdx.y * 32, c0 = blockIdx.x * 32;
    #pragma unroll
    for (int i = 0; i < 4; i++)
        tile[ty + 8*i][tx] = W[(size_t)(r0 + ty + 8*i) * N + c0 + tx];
    __syncthreads();
    #pragma unroll
    for (int i = 0; i < 4; i++)
        Wt[(size_t)(c0 + ty + 8*i) * K + r0 + tx] = (short)f2bf(tile[tx][ty + 8*i]);
}

// ---------------- V transpose: vT[(hd)*2 + b][s] = qkv[b*S+s][4096+hd] ----------------
__global__ __launch_bounds__(256) void vtrans_kernel(const short* __restrict__ qkv,
        short* __restrict__ vT) {
    __shared__ short tile[32][33];
    int t = threadIdx.x;
    int tx = t & 31, ty = t >> 5;
    int c0 = blockIdx.x * 32;          // hd
    int r0 = blockIdx.y * 32;          // s
    int b  = blockIdx.z;
    #pragma unroll
    for (int i = 0; i < 4; i++)
        tile[ty + 8*i][tx] = qkv[(size_t)(b*S_ + r0 + ty + 8*i) * LDQ + 4096 + c0 + tx];
    __syncthreads();
    #pragma unroll
    for (int i = 0; i < 4; i++)
        vT[((size_t)(c0 + ty + 8*i) * 2 + b) * S_ + r0 + tx] = tile[tx][ty + 8*i];
}

// ---------------- LayerNorm fp32 in -> bf16 out ----------------
__global__ __launch_bounds__(256) void ln_kernel(const float* __restrict__ x,
                const float* __restrict__ g, const float* __restrict__ b,
                short* __restrict__ out) {
    int row = blockIdx.x;
    const float* xr = x + (size_t)row * HD;
    short* orow = out + (size_t)row * HD;
    int t = threadIdx.x;

    float4 v0 = ((const float4*)xr)[t];
    float4 v1 = ((const float4*)xr)[t + 256];
    float s  = v0.x + v0.y + v0.z + v0.w + v1.x + v1.y + v1.z + v1.w;
    float ss = v0.x*v0.x + v0.y*v0.y + v0.z*v0.z + v0.w*v0.w
             + v1.x*v1.x + v1.y*v1.y + v1.z*v1.z + v1.w*v1.w;

    #pragma unroll
    for (int off = 1; off < 64; off <<= 1) {
        s  += __shfl_xor(s,  off, 64);
        ss += __shfl_xor(ss, off, 64);
    }
    __shared__ float ws_s[4], ws_q[4];
    int wid = t >> 6;
    if ((t & 63) == 0) { ws_s[wid] = s; ws_q[wid] = ss; }
    __syncthreads();
    s  = ws_s[0] + ws_s[1] + ws_s[2] + ws_s[3];
    ss = ws_q[0] + ws_q[1] + ws_q[2] + ws_q[3];

    float mu  = s * (1.0f / HD);
    float var = ss * (1.0f / HD) - mu * mu;
    float rs  = rsqrtf(var + 1e-5f);

    float4 g0 = ((const float4*)g)[t];
    float4 g1 = ((const float4*)g)[t + 256];
    float4 b0 = ((const float4*)b)[t];
    float4 b1 = ((const float4*)b)[t + 256];
    s16x4 o0, o1;
    o0.x = (short)f2bf((v0.x - mu) * rs * g0.x + b0.x);
    o0.y = (short)f2bf((v0.y - mu) * rs * g0.y + b0.y);
    o0.z = (short)f2bf((v0.z - mu) * rs * g0.z + b0.z);
    o0.w = (short)f2bf((v0.w - mu) * rs * g0.w + b0.w);
    o1.x = (short)f2bf((v1.x - mu) * rs * g1.x + b1.x);
    o1.y = (short)f2bf((v1.y - mu) * rs * g1.y + b1.y);
    o1.z = (short)f2bf((v1.z - mu) * rs * g1.z + b1.z);
    o1.w = (short)f2bf((v1.w - mu) * rs * g1.w + b1.w);
    ((s16x4*)orow)[t]       = o0;
    ((s16x4*)orow)[t + 256] = o1;
}

// ---------------- bf16 MFMA GEMM (m97 structure): C = epi(A @ Bt^T) ----------------
template<bool OUTBF16, bool BIAS, bool RES, bool GELU>
__global__ __launch_bounds__(256) void gemm_bf16(
        const short* __restrict__ A, const short* __restrict__ Bt,
        const float* __restrict__ bias, const float* __restrict__ res,
        void* __restrict__ Cout, int M, int N, int K) {
    __shared__ __align__(16) short As[128*64];
    __shared__ __align__(16) short Bs[128*64];
    int t = threadIdx.x;
    int wave = t >> 6, lane = t & 63;
    int l4 = lane >> 4, lm = lane & 15;
    int wr = wave >> 1, wc = wave & 1;
    int m0 = blockIdx.y * 128, n0 = blockIdx.x * 128;

    f32x4 acc[4][4];
    #pragma unroll
    for (int i = 0; i < 4; i++)
        #pragma unroll
        for (int j = 0; j < 4; j++) acc[i][j] = (f32x4){0.f, 0.f, 0.f, 0.f};

    const char* Ab = (const char*)A;
    const char* Bb = (const char*)Bt;

    for (int k0 = 0; k0 < K; k0 += 64) {
        #pragma unroll
        for (int L = 0; L < 4; L++) {
            int c   = (wave*4 + L) * 64 + lane;   // chunk 0..1023
            int row = c >> 3;
            gload_lds16(Ab + ((size_t)(m0 + row) * K + k0) * 2 + (c & 7) * 16,
                        (char*)As + (wave*4 + L) * 1024);
            gload_lds16(Bb + ((size_t)(n0 + row) * K + k0) * 2 + (c & 7) * 16,
                        (char*)Bs + (wave*4 + L) * 1024);
        }
        __syncthreads();
        #pragma unroll
        for (int kk = 0; kk < 2; kk++) {
            bf16x8 a[4], b[4];
            #pragma unroll
            for (int m = 0; m < 4; m++) {
                int row = wr*64 + m*16 + lm;
                a[m] = *(const bf16x8*)((const char*)As + row*128 + kk*64 + l4*16);
            }
            #pragma unroll
            for (int n = 0; n < 4; n++) {
                int row = wc*64 + n*16 + lm;
                b[n] = *(const bf16x8*)((const char*)Bs + row*128 + kk*64 + l4*16);
            }
            #pragma unroll
            for (int m = 0; m < 4; m++)
                #pragma unroll
                for (int n = 0; n < 4; n++)
                    acc[m][n] = __builtin_amdgcn_mfma_f32_16x16x32_bf16(a[m], b[n], acc[m][n], 0, 0, 0);
        }
        __syncthreads();
    }

    #pragma unroll
    for (int n = 0; n < 4; n++) {
        int colb = n0 + wc*64 + n*16 + lm;
        float bv = BIAS ? bias[colb] : 0.f;
        #pragma unroll
        for (int m = 0; m < 4; m++) {
            #pragma unroll
            for (int r = 0; r < 4; r++) {
                int row = m0 + wr*64 + m*16 + l4*4 + r;
                float v = acc[m][n][r] + bv;
                if (GELU) v = 0.5f * v * (1.0f + erff(v * 0.70710678118654752f));
                size_t off = (size_t)row * N + colb;
                if (RES) v += res[off];
                if (OUTBF16) ((short*)Cout)[off] = (short)f2bf(v);
                else         ((float*)Cout)[off] = v;
            }
        }
    }
}

// ---------------- MFMA flash attention (conflict-free LDS) ----------------
// 4 waves x 16 q-rows; KV tiles of 64. K and V^T staged linear via global_load_lds.
__global__ __launch_bounds__(256) void attn_kernel(
        const short* __restrict__ qkv, const short* __restrict__ vT,
        const float* __restrict__ mask, short* __restrict__ ctx) {
    __shared__ __align__(16) short Ks[64*128];   // [kv][d] linear
    __shared__ __align__(16) short Vt[128*64];   // [d][kv] linear
    __shared__ __align__(16) short Ps[4][16*72]; // per-wave P, pitch 72
    int t = threadIdx.x;
    int wave = t >> 6, lane = t & 63;
    int l4 = lane >> 4, lm = lane & 15;
    int q0 = blockIdx.x * 64, h = blockIdx.y, zb = blockIdx.z;
    const float scale = 0.08838834764831845f;  // 1/sqrt(128)

    // Q fragments in registers (wave's 16 q-rows), loaded once
    bf16x8 aq[4];
    {
        const short* qrow = qkv + (size_t)(zb*S_ + q0 + wave*16 + lm) * LDQ + h*DH_;
        #pragma unroll
        for (int ks = 0; ks < 4; ks++)
            aq[ks] = *(const bf16x8*)(qrow + ks*32 + l4*8);
    }

    float m_r[4], l_r[4];
    #pragma unroll
    for (int r = 0; r < 4; r++) { m_r[r] = -INFINITY; l_r[r] = 0.f; }
    f32x4 o[8];
    #pragma unroll
    for (int i = 0; i < 8; i++) o[i] = (f32x4){0.f, 0.f, 0.f, 0.f};

    for (int kv0 = 0; kv0 < S_; kv0 += 64) {
        __syncthreads();
        // stage K [64][128] (1024 chunks) + V^T [128][64] (1024 chunks), linear
        #pragma unroll
        for (int L = 0; L < 4; L++) {
            int c = (wave*4 + L)*64 + lane;
            int krow = c >> 4, koff = c & 15;
            gload_lds16(qkv + (size_t)(zb*S_ + kv0 + krow)*LDQ + 2048 + h*DH_ + koff*8,
                        (char*)Ks + c*16);
            int drow = c >> 3, doff = c & 7;
            gload_lds16(vT + ((size_t)(h*DH_ + drow)*2 + zb)*S_ + kv0 + doff*8,
                        (char*)Vt + c*16);
        }
        __syncthreads();

        // ---- QK^T: 16 q-rows x 64 kv-cols per wave ----
        f32x4 s[4];
        #pragma unroll
        for (int nb = 0; nb < 4; nb++) s[nb] = (f32x4){0.f, 0.f, 0.f, 0.f};
        #pragma unroll
        for (int nb = 0; nb < 4; nb++) {
            int row = nb*16 + lm;
            #pragma unroll
            for (int ks = 0; ks < 4; ks++) {
                bf16x8 bk = *(const bf16x8*)((const char*)Ks + row*256 + ks*64 + l4*16);
                s[nb] = __builtin_amdgcn_mfma_f32_16x16x32_bf16(aq[ks], bk, s[nb], 0, 0, 0);
            }
        }

        // ---- online softmax (lane's rows q=l4*4+r; cols nb*16+lm) ----
        float mk[4];
        #pragma unroll
        for (int nb = 0; nb < 4; nb++) mk[nb] = mask[(size_t)zb*S_ + kv0 + nb*16 + lm];

        float pv_[4][4], fac[4];
        #pragma unroll
        for (int r = 0; r < 4; r++) {
            float vmax = -INFINITY;
            #pragma unroll
            for (int nb = 0; nb < 4; nb++) {
                float v = s[nb][r] * scale + mk[nb];
                pv_[r][nb] = v;
                vmax = fmaxf(vmax, v);
            }
            vmax = fmaxf(vmax, __shfl_xor(vmax, 1, 64));
            vmax = fmaxf(vmax, __shfl_xor(vmax, 2, 64));
            vmax = fmaxf(vmax, __shfl_xor(vmax, 4, 64));
            vmax = fmaxf(vmax, __shfl_xor(vmax, 8, 64));
            float nm = fmaxf(m_r[r], vmax);
            fac[r] = __expf(m_r[r] - nm);
            float ps = 0.f;
            #pragma unroll
            for (int nb = 0; nb < 4; nb++) {
                float e = __expf(pv_[r][nb] - nm);
                pv_[r][nb] = e;
                ps += e;
            }
            ps += __shfl_xor(ps, 1, 64);
            ps += __shfl_xor(ps, 2, 64);
            ps += __shfl_xor(ps, 4, 64);
            ps += __shfl_xor(ps, 8, 64);
            l_r[r] = l_r[r] * fac[r] + ps;
            m_r[r] = nm;
        }
        #pragma unroll
        for (int i = 0; i < 8; i++)
            #pragma unroll
            for (int r = 0; r < 4; r++) o[i][r] *= fac[r];

        // ---- P -> per-wave LDS (bf16, padded pitch 72) ----
        short* Pw = (short*)Ps[wave];
        #pragma unroll
        for (int r = 0; r < 4; r++)
            #pragma unroll
            for (int nb = 0; nb < 4; nb++)
                Pw[(l4*4 + r)*72 + nb*16 + lm] = (short)f2bf(pv_[r][nb]);

        // ---- PV: o[16 q][128 d] += P[16][64] @ V[64][128] ----
        #pragma unroll
        for (int ks = 0; ks < 2; ks++) {
            bf16x8 ap = *(const bf16x8*)(Pw + lm*72 + ks*32 + l4*8);
            #pragma unroll
            for (int nd = 0; nd < 8; nd++) {
                bf16x8 bv = *(const bf16x8*)((const char*)Vt + (nd*16 + lm)*128 + ks*64 + l4*16);
                o[nd] = __builtin_amdgcn_mfma_f32_16x16x32_bf16(ap, bv, o[nd], 0, 0, 0);
            }
        }
    }

    float inv[4];
    #pragma unroll
    for (int r = 0; r < 4; r++) inv[r] = 1.0f / l_r[r];
    #pragma unroll
    for (int nd = 0; nd < 8; nd++) {
        #pragma unroll
        for (int r = 0; r < 4; r++) {
            size_t row = (size_t)(zb*S_ + q0 + wave*16 + l4*4 + r);
            ctx[row * HD + h*DH_ + nd*16 + lm] = (short)f2bf(o[nd][r] * inv[r]);
        }
    }
}

extern "C" void kernel_launch(void* const* d_in, const int* in_sizes, int n_in,
                              void* d_out, int out_size, void* d_ws, size_t ws_size,
                              hipStream_t stream) {
    const float* x      = (const float*)d_in[0];
    const float* mask   = (const float*)d_in[1];
    const float* ln1_g  = (const float*)d_in[2];
    const float* ln1_b  = (const float*)d_in[3];
    const float* ln2_g  = (const float*)d_in[4];
    const float* ln2_b  = (const float*)d_in[5];
    const float* Wq     = (const float*)d_in[6];
    const float* Wk     = (const float*)d_in[7];
    const float* Wv     = (const float*)d_in[8];
    const float* Wo     = (const float*)d_in[9];
    const float* W1     = (const float*)d_in[10];
    const float* b1     = (const float*)d_in[11];
    const float* W2     = (const float*)d_in[12];
    const float* b2     = (const float*)d_in[13];
    float* out = (float*)d_out;

    char* ws = (char*)d_ws;
    size_t off = 0;
    const size_t WSQ  = (size_t)HD * HD * 2;        // 8 MiB
    const size_t WFF  = (size_t)HD * FF_ * 2;       // 32 MiB
    const size_t ACTB = (size_t)MROWS * HD * 2;     // 16 MiB
    short* WqkvT = (short*)(ws + off); off += 3 * WSQ;             // 24 MiB
    short* WoT   = (short*)(ws + off); off += WSQ;                 // 8
    short* W1T   = (short*)(ws + off); off += WFF;                 // 32
    short* W2T   = (short*)(ws + off); off += WFF;                 // 32
    short* hb    = (short*)(ws + off); off += ACTB;                // 16
    short* qkv   = (short*)(ws + off); off += (size_t)MROWS * LDQ * 2;  // 48
    short* vTb   = (short*)(ws + off); off += (size_t)HD * B_ * S_ * 2; // 16
    float* x1    = (float*)(ws + off); off += (size_t)MROWS * HD * 4;   // 32  (total 208 MiB)
    short* cb    = WqkvT;   // overlay: ctx over dead WqkvT (16 <= 24 MiB)
    short* act   = qkv;     // overlay: act (64 MiB) over dead qkv+vT

    dim3 blk(256);

    // weight convert+transpose (bf16, [N][K])
    trcvt_kernel<<<dim3(HD/32,  HD/32),  blk, 0, stream>>>(Wq, WqkvT,                 HD, HD);
    trcvt_kernel<<<dim3(HD/32,  HD/32),  blk, 0, stream>>>(Wk, WqkvT + (size_t)HD*HD, HD, HD);
    trcvt_kernel<<<dim3(HD/32,  HD/32),  blk, 0, stream>>>(Wv, WqkvT + (size_t)2*HD*HD, HD, HD);
    trcvt_kernel<<<dim3(HD/32,  HD/32),  blk, 0, stream>>>(Wo, WoT, HD, HD);
    trcvt_kernel<<<dim3(FF_/32, HD/32),  blk, 0, stream>>>(W1, W1T, HD, FF_);
    trcvt_kernel<<<dim3(HD/32,  FF_/32), blk, 0, stream>>>(W2, W2T, FF_, HD);

    // 1) h = LN1(x) -> bf16
    ln_kernel<<<MROWS, blk, 0, stream>>>(x, ln1_g, ln1_b, hb);

    // 2) qkv = h @ [Wq|Wk|Wv]  (fused, N=6144)
    gemm_bf16<true,false,false,false><<<dim3(LDQ/128, MROWS/128), blk, 0, stream>>>(
        hb, WqkvT, nullptr, nullptr, qkv, MROWS, LDQ, HD);

    // 2.5) vT[hd][b][s] = qkv v-part transposed
    vtrans_kernel<<<dim3(HD/32, S_/32, B_), blk, 0, stream>>>(qkv, vTb);

    // 3) ctx = softmax(qk^T*scale + mask) v  -> bf16 (over WqkvT)
    attn_kernel<<<dim3(S_/64, NH_, B_), blk, 0, stream>>>(qkv, vTb, mask, cb);

    // 4) x1 = x + ctx @ Wo  (f32)
    dim3 gsq(HD/128, MROWS/128);
    gemm_bf16<false,false,true,false><<<gsq, blk, 0, stream>>>(cb, WoT, nullptr, x, x1, MROWS, HD, HD);

    // 5) h2 = LN2(x1) -> bf16 (reuse hb)
    ln_kernel<<<MROWS, blk, 0, stream>>>(x1, ln2_g, ln2_b, hb);

    // 6) act = gelu(h2 @ W1 + b1) -> bf16 (overlays qkv+vT)
    gemm_bf16<true,true,false,true><<<dim3(FF_/128, MROWS/128), blk, 0, stream>>>(
        hb, W1T, b1, nullptr, act, MROWS, FF_, HD);

    // 7) out = x1 + act @ W2 + b2  (f32)
    gemm_bf16<false,true,true,false><<<gsq, blk, 0, stream>>>(act, W2T, b2, x1, out, MROWS, HD, FF_);
}

// Round 6
// 936.083 us; speedup vs baseline: 1.2785x; 1.1215x over previous
//
#include <hip/hip_runtime.h>
#include <math.h>

#define B_ 2
#define S_ 2048
#define HD 2048
#define NH_ 16
#define DH_ 128
#define FF_ 8192
#define MROWS (B_*S_)   // 4096
#define LDQ 6144        // fused qkv row stride

typedef __attribute__((ext_vector_type(8))) short bf16x8;
typedef __attribute__((ext_vector_type(4))) short s16x4;
typedef __attribute__((ext_vector_type(4))) float f32x4;

static __device__ __forceinline__ unsigned short f2bf(float f) {
    unsigned u = __float_as_uint(f);
    u += 0x7fffu + ((u >> 16) & 1u);   // round-to-nearest-even
    return (unsigned short)(u >> 16);
}

static __device__ __forceinline__ void gload_lds16(const void* g, void* lds) {
    __builtin_amdgcn_global_load_lds((const __attribute__((address_space(1))) void*)g,
                                     (__attribute__((address_space(3))) void*)lds, 16, 0, 0);
}

// ---------------- weight fp32 -> bf16 transpose: Wt[N][K] = bf16(W[K][N]) ----------------
__global__ __launch_bounds__(256) void trcvt_kernel(const float* __restrict__ W,
        short* __restrict__ Wt, int K, int N) {
    __shared__ float tile[32][33];
    int t = threadIdx.x;
    int tx = t & 31, ty = t >> 5;      // ty 0..7
    int r0 = blockIdx.y * 32, c0 = blockIdx.x * 32;
    #pragma unroll
    for (int i = 0; i < 4; i++)
        tile[ty + 8*i][tx] = W[(size_t)(r0 + ty + 8*i) * N + c0 + tx];
    __syncthreads();
    #pragma unroll
    for (int i = 0; i < 4; i++)
        Wt[(size_t)(c0 + ty + 8*i) * K + r0 + tx] = (short)f2bf(tile[tx][ty + 8*i]);
}

// ---------------- V transpose: vT[(hd)*2 + b][s] = qkv[b*S+s][4096+hd] ----------------
__global__ __launch_bounds__(256) void vtrans_kernel(const short* __restrict__ qkv,
        short* __restrict__ vT) {
    __shared__ short tile[32][33];
    int t = threadIdx.x;
    int tx = t & 31, ty = t >> 5;
    int c0 = blockIdx.x * 32;          // hd
    int r0 = blockIdx.y * 32;          // s
    int b  = blockIdx.z;
    #pragma unroll
    for (int i = 0; i < 4; i++)
        tile[ty + 8*i][tx] = qkv[(size_t)(b*S_ + r0 + ty + 8*i) * LDQ + 4096 + c0 + tx];
    __syncthreads();
    #pragma unroll
    for (int i = 0; i < 4; i++)
        vT[((size_t)(c0 + ty + 8*i) * 2 + b) * S_ + r0 + tx] = tile[tx][ty + 8*i];
}

// ---------------- LayerNorm fp32 in -> bf16 out ----------------
__global__ __launch_bounds__(256) void ln_kernel(const float* __restrict__ x,
                const float* __restrict__ g, const float* __restrict__ b,
                short* __restrict__ out) {
    int row = blockIdx.x;
    const float* xr = x + (size_t)row * HD;
    short* orow = out + (size_t)row * HD;
    int t = threadIdx.x;

    float4 v0 = ((const float4*)xr)[t];
    float4 v1 = ((const float4*)xr)[t + 256];
    float s  = v0.x + v0.y + v0.z + v0.w + v1.x + v1.y + v1.z + v1.w;
    float ss = v0.x*v0.x + v0.y*v0.y + v0.z*v0.z + v0.w*v0.w
             + v1.x*v1.x + v1.y*v1.y + v1.z*v1.z + v1.w*v1.w;

    #pragma unroll
    for (int off = 1; off < 64; off <<= 1) {
        s  += __shfl_xor(s,  off, 64);
        ss += __shfl_xor(ss, off, 64);
    }
    __shared__ float ws_s[4], ws_q[4];
    int wid = t >> 6;
    if ((t & 63) == 0) { ws_s[wid] = s; ws_q[wid] = ss; }
    __syncthreads();
    s  = ws_s[0] + ws_s[1] + ws_s[2] + ws_s[3];
    ss = ws_q[0] + ws_q[1] + ws_q[2] + ws_q[3];

    float mu  = s * (1.0f / HD);
    float var = ss * (1.0f / HD) - mu * mu;
    float rs  = rsqrtf(var + 1e-5f);

    float4 g0 = ((const float4*)g)[t];
    float4 g1 = ((const float4*)g)[t + 256];
    float4 b0 = ((const float4*)b)[t];
    float4 b1 = ((const float4*)b)[t + 256];
    s16x4 o0, o1;
    o0.x = (short)f2bf((v0.x - mu) * rs * g0.x + b0.x);
    o0.y = (short)f2bf((v0.y - mu) * rs * g0.y + b0.y);
    o0.z = (short)f2bf((v0.z - mu) * rs * g0.z + b0.z);
    o0.w = (short)f2bf((v0.w - mu) * rs * g0.w + b0.w);
    o1.x = (short)f2bf((v1.x - mu) * rs * g1.x + b1.x);
    o1.y = (short)f2bf((v1.y - mu) * rs * g1.y + b1.y);
    o1.z = (short)f2bf((v1.z - mu) * rs * g1.z + b1.z);
    o1.w = (short)f2bf((v1.w - mu) * rs * g1.w + b1.w);
    ((s16x4*)orow)[t]       = o0;
    ((s16x4*)orow)[t + 256] = o1;
}

// ---------------- bf16 MFMA GEMM (m97 structure): C = epi(A @ Bt^T) ----------------
template<bool OUTBF16, bool BIAS, bool RES, bool GELU>
__global__ __launch_bounds__(256) void gemm_bf16(
        const short* __restrict__ A, const short* __restrict__ Bt,
        const float* __restrict__ bias, const float* __restrict__ res,
        void* __restrict__ Cout, int M, int N, int K) {
    __shared__ __align__(16) short As[128*64];
    __shared__ __align__(16) short Bs[128*64];
    int t = threadIdx.x;
    int wave = t >> 6, lane = t & 63;
    int l4 = lane >> 4, lm = lane & 15;
    int wr = wave >> 1, wc = wave & 1;
    int m0 = blockIdx.y * 128, n0 = blockIdx.x * 128;

    f32x4 acc[4][4];
    #pragma unroll
    for (int i = 0; i < 4; i++)
        #pragma unroll
        for (int j = 0; j < 4; j++) acc[i][j] = (f32x4){0.f, 0.f, 0.f, 0.f};

    const char* Ab = (const char*)A;
    const char* Bb = (const char*)Bt;

    for (int k0 = 0; k0 < K; k0 += 64) {
        #pragma unroll
        for (int L = 0; L < 4; L++) {
            int c   = (wave*4 + L) * 64 + lane;   // chunk 0..1023
            int row = c >> 3;
            gload_lds16(Ab + ((size_t)(m0 + row) * K + k0) * 2 + (c & 7) * 16,
                        (char*)As + (wave*4 + L) * 1024);
            gload_lds16(Bb + ((size_t)(n0 + row) * K + k0) * 2 + (c & 7) * 16,
                        (char*)Bs + (wave*4 + L) * 1024);
        }
        __syncthreads();
        #pragma unroll
        for (int kk = 0; kk < 2; kk++) {
            bf16x8 a[4], b[4];
            #pragma unroll
            for (int m = 0; m < 4; m++) {
                int row = wr*64 + m*16 + lm;
                a[m] = *(const bf16x8*)((const char*)As + row*128 + kk*64 + l4*16);
            }
            #pragma unroll
            for (int n = 0; n < 4; n++) {
                int row = wc*64 + n*16 + lm;
                b[n] = *(const bf16x8*)((const char*)Bs + row*128 + kk*64 + l4*16);
            }
            #pragma unroll
            for (int m = 0; m < 4; m++)
                #pragma unroll
                for (int n = 0; n < 4; n++)
                    acc[m][n] = __builtin_amdgcn_mfma_f32_16x16x32_bf16(a[m], b[n], acc[m][n], 0, 0, 0);
        }
        __syncthreads();
    }

    #pragma unroll
    for (int n = 0; n < 4; n++) {
        int colb = n0 + wc*64 + n*16 + lm;
        float bv = BIAS ? bias[colb] : 0.f;
        #pragma unroll
        for (int m = 0; m < 4; m++) {
            #pragma unroll
            for (int r = 0; r < 4; r++) {
                int row = m0 + wr*64 + m*16 + l4*4 + r;
                float v = acc[m][n][r] + bv;
                if (GELU) v = 0.5f * v * (1.0f + erff(v * 0.70710678118654752f));
                size_t off = (size_t)row * N + colb;
                if (RES) v += res[off];
                if (OUTBF16) ((short*)Cout)[off] = (short)f2bf(v);
                else         ((float*)Cout)[off] = v;
            }
        }
    }
}

// ---------------- MFMA flash attention (read-side XOR-swizzled LDS) ----------------
// 4 waves x 16 q-rows; KV tiles of 64. K and V^T staged linear via global_load_lds
// with PRE-SWIZZLED global source (rule #21), reads use matching XOR swizzle.
__global__ __launch_bounds__(256) void attn_kernel(
        const short* __restrict__ qkv, const short* __restrict__ vT,
        const float* __restrict__ mask, short* __restrict__ ctx) {
    __shared__ __align__(16) short Ks[64*128];   // [kv][d], chunk-swizzled
    __shared__ __align__(16) short Vt[128*64];   // [d][kv], chunk-swizzled
    __shared__ __align__(16) short Ps[4][16*72]; // per-wave P, pitch 72
    int t = threadIdx.x;
    int wave = t >> 6, lane = t & 63;
    int l4 = lane >> 4, lm = lane & 15;
    int q0 = blockIdx.x * 64, h = blockIdx.y, zb = blockIdx.z;
    const float scale = 0.08838834764831845f;  // 1/sqrt(128)

    // Q fragments in registers (wave's 16 q-rows), loaded once
    bf16x8 aq[4];
    {
        const short* qrow = qkv + (size_t)(zb*S_ + q0 + wave*16 + lm) * LDQ + h*DH_;
        #pragma unroll
        for (int ks = 0; ks < 4; ks++)
            aq[ks] = *(const bf16x8*)(qrow + ks*32 + l4*8);
    }

    float m_r[4], l_r[4];
    #pragma unroll
    for (int r = 0; r < 4; r++) { m_r[r] = -INFINITY; l_r[r] = 0.f; }
    f32x4 o[8];
    #pragma unroll
    for (int i = 0; i < 8; i++) o[i] = (f32x4){0.f, 0.f, 0.f, 0.f};

    for (int kv0 = 0; kv0 < S_; kv0 += 64) {
        __syncthreads();
        // stage K [64][128] (16 chunks/row) + V^T [128][64] (8 chunks/row);
        // LDS dest linear, global source chunk-index inverse-swizzled.
        #pragma unroll
        for (int L = 0; L < 4; L++) {
            int c = (wave*4 + L)*64 + lane;
            int krow = c >> 4, kc = c & 15;
            int ksrc = (kc & 8) | ((kc ^ (krow & 7)) & 7);
            gload_lds16(qkv + (size_t)(zb*S_ + kv0 + krow)*LDQ + 2048 + h*DH_ + ksrc*8,
                        (char*)Ks + c*16);
            int drow = c >> 3, dc = c & 7;
            int dsrc = dc ^ (drow & 7);
            gload_lds16(vT + ((size_t)(h*DH_ + drow)*2 + zb)*S_ + kv0 + dsrc*8,
                        (char*)Vt + c*16);
        }
        __syncthreads();

        // ---- QK^T: 16 q-rows x 64 kv-cols per wave ----
        f32x4 s[4];
        #pragma unroll
        for (int nb = 0; nb < 4; nb++) s[nb] = (f32x4){0.f, 0.f, 0.f, 0.f};
        __builtin_amdgcn_s_setprio(1);
        #pragma unroll
        for (int nb = 0; nb < 4; nb++) {
            int row = nb*16 + lm;
            #pragma unroll
            for (int ks = 0; ks < 4; ks++) {
                bf16x8 bk = *(const bf16x8*)((const char*)Ks +
                              ((row*256 + ks*64 + l4*16) ^ ((row & 7) << 4)));
                s[nb] = __builtin_amdgcn_mfma_f32_16x16x32_bf16(aq[ks], bk, s[nb], 0, 0, 0);
            }
        }
        __builtin_amdgcn_s_setprio(0);

        // ---- online softmax (lane's rows q=l4*4+r; cols nb*16+lm) ----
        float mk[4];
        #pragma unroll
        for (int nb = 0; nb < 4; nb++) mk[nb] = mask[(size_t)zb*S_ + kv0 + nb*16 + lm];

        float pv_[4][4], fac[4];
        #pragma unroll
        for (int r = 0; r < 4; r++) {
            float vmax = -INFINITY;
            #pragma unroll
            for (int nb = 0; nb < 4; nb++) {
                float v = s[nb][r] * scale + mk[nb];
                pv_[r][nb] = v;
                vmax = fmaxf(vmax, v);
            }
            vmax = fmaxf(vmax, __shfl_xor(vmax, 1, 64));
            vmax = fmaxf(vmax, __shfl_xor(vmax, 2, 64));
            vmax = fmaxf(vmax, __shfl_xor(vmax, 4, 64));
            vmax = fmaxf(vmax, __shfl_xor(vmax, 8, 64));
            float nm = fmaxf(m_r[r], vmax);
            fac[r] = __expf(m_r[r] - nm);
            float ps = 0.f;
            #pragma unroll
            for (int nb = 0; nb < 4; nb++) {
                float e = __expf(pv_[r][nb] - nm);
                pv_[r][nb] = e;
                ps += e;
            }
            ps += __shfl_xor(ps, 1, 64);
            ps += __shfl_xor(ps, 2, 64);
            ps += __shfl_xor(ps, 4, 64);
            ps += __shfl_xor(ps, 8, 64);
            l_r[r] = l_r[r] * fac[r] + ps;
            m_r[r] = nm;
        }
        #pragma unroll
        for (int i = 0; i < 8; i++)
            #pragma unroll
            for (int r = 0; r < 4; r++) o[i][r] *= fac[r];

        // ---- P -> per-wave LDS (bf16, padded pitch 72) ----
        short* Pw = (short*)Ps[wave];
        #pragma unroll
        for (int r = 0; r < 4; r++)
            #pragma unroll
            for (int nb = 0; nb < 4; nb++)
                Pw[(l4*4 + r)*72 + nb*16 + lm] = (short)f2bf(pv_[r][nb]);

        // ---- PV: o[16 q][128 d] += P[16][64] @ V[64][128] ----
        __builtin_amdgcn_s_setprio(1);
        #pragma unroll
        for (int ks = 0; ks < 2; ks++) {
            bf16x8 ap = *(const bf16x8*)(Pw + lm*72 + ks*32 + l4*8);
            #pragma unroll
            for (int nd = 0; nd < 8; nd++) {
                int d = nd*16 + lm;
                bf16x8 bv = *(const bf16x8*)((const char*)Vt +
                              (((d*128) + ks*64 + l4*16) ^ ((d & 7) << 4)));
                o[nd] = __builtin_amdgcn_mfma_f32_16x16x32_bf16(ap, bv, o[nd], 0, 0, 0);
            }
        }
        __builtin_amdgcn_s_setprio(0);
    }

    float inv[4];
    #pragma unroll
    for (int r = 0; r < 4; r++) inv[r] = 1.0f / l_r[r];
    #pragma unroll
    for (int nd = 0; nd < 8; nd++) {
        #pragma unroll
        for (int r = 0; r < 4; r++) {
            size_t row = (size_t)(zb*S_ + q0 + wave*16 + l4*4 + r);
            ctx[row * HD + h*DH_ + nd*16 + lm] = (short)f2bf(o[nd][r] * inv[r]);
        }
    }
}

extern "C" void kernel_launch(void* const* d_in, const int* in_sizes, int n_in,
                              void* d_out, int out_size, void* d_ws, size_t ws_size,
                              hipStream_t stream) {
    const float* x      = (const float*)d_in[0];
    const float* mask   = (const float*)d_in[1];
    const float* ln1_g  = (const float*)d_in[2];
    const float* ln1_b  = (const float*)d_in[3];
    const float* ln2_g  = (const float*)d_in[4];
    const float* ln2_b  = (const float*)d_in[5];
    const float* Wq     = (const float*)d_in[6];
    const float* Wk     = (const float*)d_in[7];
    const float* Wv     = (const float*)d_in[8];
    const float* Wo     = (const float*)d_in[9];
    const float* W1     = (const float*)d_in[10];
    const float* b1     = (const float*)d_in[11];
    const float* W2     = (const float*)d_in[12];
    const float* b2     = (const float*)d_in[13];
    float* out = (float*)d_out;

    char* ws = (char*)d_ws;
    size_t off = 0;
    const size_t WSQ  = (size_t)HD * HD * 2;        // 8 MiB
    const size_t WFF  = (size_t)HD * FF_ * 2;       // 32 MiB
    const size_t ACTB = (size_t)MROWS * HD * 2;     // 16 MiB
    short* WqkvT = (short*)(ws + off); off += 3 * WSQ;             // 24 MiB
    short* WoT   = (short*)(ws + off); off += WSQ;                 // 8
    short* W1T   = (short*)(ws + off); off += WFF;                 // 32
    short* W2T   = (short*)(ws + off); off += WFF;                 // 32
    short* hb    = (short*)(ws + off); off += ACTB;                // 16
    short* qkv   = (short*)(ws + off); off += (size_t)MROWS * LDQ * 2;  // 48
    short* vTb   = (short*)(ws + off); off += (size_t)HD * B_ * S_ * 2; // 16
    float* x1    = (float*)(ws + off); off += (size_t)MROWS * HD * 4;   // 32  (total 208 MiB)
    short* cb    = WqkvT;   // overlay: ctx over dead WqkvT (16 <= 24 MiB)
    short* act   = qkv;     // overlay: act (64 MiB) over dead qkv+vT

    dim3 blk(256);

    // weight convert+transpose (bf16, [N][K])
    trcvt_kernel<<<dim3(HD/32,  HD/32),  blk, 0, stream>>>(Wq, WqkvT,                 HD, HD);
    trcvt_kernel<<<dim3(HD/32,  HD/32),  blk, 0, stream>>>(Wk, WqkvT + (size_t)HD*HD, HD, HD);
    trcvt_kernel<<<dim3(HD/32,  HD/32),  blk, 0, stream>>>(Wv, WqkvT + (size_t)2*HD*HD, HD, HD);
    trcvt_kernel<<<dim3(HD/32,  HD/32),  blk, 0, stream>>>(Wo, WoT, HD, HD);
    trcvt_kernel<<<dim3(FF_/32, HD/32),  blk, 0, stream>>>(W1, W1T, HD, FF_);
    trcvt_kernel<<<dim3(HD/32,  FF_/32), blk, 0, stream>>>(W2, W2T, FF_, HD);

    // 1) h = LN1(x) -> bf16
    ln_kernel<<<MROWS, blk, 0, stream>>>(x, ln1_g, ln1_b, hb);

    // 2) qkv = h @ [Wq|Wk|Wv]  (fused, N=6144)
    gemm_bf16<true,false,false,false><<<dim3(LDQ/128, MROWS/128), blk, 0, stream>>>(
        hb, WqkvT, nullptr, nullptr, qkv, MROWS, LDQ, HD);

    // 2.5) vT[hd][b][s] = qkv v-part transposed
    vtrans_kernel<<<dim3(HD/32, S_/32, B_), blk, 0, stream>>>(qkv, vTb);

    // 3) ctx = softmax(qk^T*scale + mask) v  -> bf16 (over WqkvT)
    attn_kernel<<<dim3(S_/64, NH_, B_), blk, 0, stream>>>(qkv, vTb, mask, cb);

    // 4) x1 = x + ctx @ Wo  (f32)
    dim3 gsq(HD/128, MROWS/128);
    gemm_bf16<false,false,true,false><<<gsq, blk, 0, stream>>>(cb, WoT, nullptr, x, x1, MROWS, HD, HD);

    // 5) h2 = LN2(x1) -> bf16 (reuse hb)
    ln_kernel<<<MROWS, blk, 0, stream>>>(x1, ln2_g, ln2_b, hb);

    // 6) act = gelu(h2 @ W1 + b1) -> bf16 (overlays qkv+vT)
    gemm_bf16<true,true,false,true><<<dim3(FF_/128, MROWS/128), blk, 0, stream>>>(
        hb, W1T, b1, nullptr, act, MROWS, FF_, HD);

    // 7) out = x1 + act @ W2 + b2  (f32)
    gemm_bf16<false,true,true,false><<<gsq, blk, 0, stream>>>(act, W2T, b2, x1, out, MROWS, HD, FF_);
}

// Round 8
// 874.584 us; speedup vs baseline: 1.3684x; 1.0703x over previous
//
#include <hip/hip_runtime.h>
#include <math.h>

#define B_ 2
#define S_ 2048
#define HD 2048
#define NH_ 16
#define DH_ 128
#define FF_ 8192
#define MROWS (B_*S_)   // 4096
#define LDQ 6144        // fused qkv row stride

typedef __attribute__((ext_vector_type(8))) short bf16x8;
typedef __attribute__((ext_vector_type(4))) short s16x4;
typedef __attribute__((ext_vector_type(4))) float f32x4;

static __device__ __forceinline__ unsigned short f2bf(float f) {
    unsigned u = __float_as_uint(f);
    u += 0x7fffu + ((u >> 16) & 1u);   // round-to-nearest-even
    return (unsigned short)(u >> 16);
}

static __device__ __forceinline__ void gload_lds16(const void* g, void* lds) {
    __builtin_amdgcn_global_load_lds((const __attribute__((address_space(1))) void*)g,
                                     (__attribute__((address_space(3))) void*)lds, 16, 0, 0);
}

// ---------------- weight fp32 -> bf16 transpose: Wt[N][K] = bf16(W[K][N]) ----------------
__global__ __launch_bounds__(256) void trcvt_kernel(const float* __restrict__ W,
        short* __restrict__ Wt, int K, int N) {
    __shared__ float tile[32][33];
    int t = threadIdx.x;
    int tx = t & 31, ty = t >> 5;      // ty 0..7
    int r0 = blockIdx.y * 32, c0 = blockIdx.x * 32;
    #pragma unroll
    for (int i = 0; i < 4; i++)
        tile[ty + 8*i][tx] = W[(size_t)(r0 + ty + 8*i) * N + c0 + tx];
    __syncthreads();
    #pragma unroll
    for (int i = 0; i < 4; i++)
        Wt[(size_t)(c0 + ty + 8*i) * K + r0 + tx] = (short)f2bf(tile[tx][ty + 8*i]);
}

// ---------------- V transpose: vT[(hd)*2 + b][s] = qkv[b*S+s][4096+hd] ----------------
__global__ __launch_bounds__(256) void vtrans_kernel(const short* __restrict__ qkv,
        short* __restrict__ vT) {
    __shared__ short tile[32][33];
    int t = threadIdx.x;
    int tx = t & 31, ty = t >> 5;
    int c0 = blockIdx.x * 32;          // hd
    int r0 = blockIdx.y * 32;          // s
    int b  = blockIdx.z;
    #pragma unroll
    for (int i = 0; i < 4; i++)
        tile[ty + 8*i][tx] = qkv[(size_t)(b*S_ + r0 + ty + 8*i) * LDQ + 4096 + c0 + tx];
    __syncthreads();
    #pragma unroll
    for (int i = 0; i < 4; i++)
        vT[((size_t)(c0 + ty + 8*i) * 2 + b) * S_ + r0 + tx] = tile[tx][ty + 8*i];
}

// ---------------- LayerNorm fp32 in -> bf16 out ----------------
__global__ __launch_bounds__(256) void ln_kernel(const float* __restrict__ x,
                const float* __restrict__ g, const float* __restrict__ b,
                short* __restrict__ out) {
    int row = blockIdx.x;
    const float* xr = x + (size_t)row * HD;
    short* orow = out + (size_t)row * HD;
    int t = threadIdx.x;

    float4 v0 = ((const float4*)xr)[t];
    float4 v1 = ((const float4*)xr)[t + 256];
    float s  = v0.x + v0.y + v0.z + v0.w + v1.x + v1.y + v1.z + v1.w;
    float ss = v0.x*v0.x + v0.y*v0.y + v0.z*v0.z + v0.w*v0.w
             + v1.x*v1.x + v1.y*v1.y + v1.z*v1.z + v1.w*v1.w;

    #pragma unroll
    for (int off = 1; off < 64; off <<= 1) {
        s  += __shfl_xor(s,  off, 64);
        ss += __shfl_xor(ss, off, 64);
    }
    __shared__ float ws_s[4], ws_q[4];
    int wid = t >> 6;
    if ((t & 63) == 0) { ws_s[wid] = s; ws_q[wid] = ss; }
    __syncthreads();
    s  = ws_s[0] + ws_s[1] + ws_s[2] + ws_s[3];
    ss = ws_q[0] + ws_q[1] + ws_q[2] + ws_q[3];

    float mu  = s * (1.0f / HD);
    float var = ss * (1.0f / HD) - mu * mu;
    float rs  = rsqrtf(var + 1e-5f);

    float4 g0 = ((const float4*)g)[t];
    float4 g1 = ((const float4*)g)[t + 256];
    float4 b0 = ((const float4*)b)[t];
    float4 b1 = ((const float4*)b)[t + 256];
    s16x4 o0, o1;
    o0.x = (short)f2bf((v0.x - mu) * rs * g0.x + b0.x);
    o0.y = (short)f2bf((v0.y - mu) * rs * g0.y + b0.y);
    o0.z = (short)f2bf((v0.z - mu) * rs * g0.z + b0.z);
    o0.w = (short)f2bf((v0.w - mu) * rs * g0.w + b0.w);
    o1.x = (short)f2bf((v1.x - mu) * rs * g1.x + b1.x);
    o1.y = (short)f2bf((v1.y - mu) * rs * g1.y + b1.y);
    o1.z = (short)f2bf((v1.z - mu) * rs * g1.z + b1.z);
    o1.w = (short)f2bf((v1.w - mu) * rs * g1.w + b1.w);
    ((s16x4*)orow)[t]       = o0;
    ((s16x4*)orow)[t + 256] = o1;
}

// =================== 256-col 8-phase MFMA GEMM (HK-style, plain HIP) ===================
// C[M][N] = epi(A[M][K] @ Bt[N][K]^T). BN=256 fixed, BM templated (256 or 128).
// 512 thr = 8 waves (2 M x 4 N); per-wave out = (BM/2) x 64.
// K-tile BK=64 split into 2 k-half units (rows x 32) per operand; per phase:
// {ds_read frags | stage 1 unit via global_load_lds} -> bar -> setprio -> MFMA -> bar.
// Counted vmcnt(LA+2) at phases 4 and 8 only (ledger-verified; never drains to 0).
// Chunk XOR swizzle (c ^ (row&3) ^ ((row>>2)&3)) applied to global SOURCE + LDS read.
#define NOCK (void)0
#define CKV() { if constexpr (BM == 256) asm volatile("s_waitcnt vmcnt(4)" ::: "memory"); \
                else                     asm volatile("s_waitcnt vmcnt(3)" ::: "memory"); }

#define GPH(BUF, KK, MH, LOADB, STG, CK) {                                        \
    bf16x8 av[MHF];                                                               \
    _Pragma("unroll") for (int i = 0; i < MHF; i++) {                             \
        int row = wm * (BM/2) + (MH * MHF + i) * 16 + lm;                         \
        int slot = (l4 ^ (row & 3) ^ ((row >> 2) & 3)) & 3;                       \
        av[i] = *(const bf16x8*)((const char*)ldsA[BUF][KK] + row * 64 + slot * 16); \
    }                                                                             \
    if (LOADB) {                                                                  \
        _Pragma("unroll") for (int n = 0; n < 4; n++) {                           \
            int row = wn * 64 + n * 16 + lm;                                      \
            int slot = (l4 ^ (row & 3) ^ ((row >> 2) & 3)) & 3;                   \
            bv[n] = *(const bf16x8*)((const char*)ldsB[BUF][KK] + row * 64 + slot * 16); \
        }                                                                         \
    }                                                                             \
    STG;                                                                          \
    CK;                                                                           \
    __builtin_amdgcn_s_barrier();                                                 \
    __builtin_amdgcn_sched_barrier(0);                                            \
    __builtin_amdgcn_s_setprio(1);                                                \
    _Pragma("unroll") for (int i = 0; i < MHF; i++)                               \
        _Pragma("unroll") for (int n = 0; n < 4; n++)                             \
            acc[MH * MHF + i][n] = __builtin_amdgcn_mfma_f32_16x16x32_bf16(       \
                av[i], bv[n], acc[MH * MHF + i][n], 0, 0, 0);                     \
    __builtin_amdgcn_s_setprio(0);                                                \
    __builtin_amdgcn_s_barrier();                                                 \
    __builtin_amdgcn_sched_barrier(0);                                            \
}

template<int BM, bool OUTBF16, bool BIAS, bool RES, bool GELU>
__global__ __launch_bounds__(512, 2) void gemm256(
        const short* __restrict__ A, const short* __restrict__ Bt,
        const float* __restrict__ bias, const float* __restrict__ res,
        void* __restrict__ Cout, int M, int N, int K) {
    constexpr int MFR = BM / 32;      // m-frags per wave
    constexpr int MHF = MFR / 2;      // m-frags per phase
    constexpr int LA  = BM / 128;     // gload_lds per thread per A-unit
    __shared__ __align__(16) short ldsA[2][2][BM * 32];
    __shared__ __align__(16) short ldsB[2][2][256 * 32];

    int tid = threadIdx.x;
    int wave = tid >> 6, lane = tid & 63;
    int l4 = lane >> 4, lm = lane & 15;
    int wm = wave >> 2, wn = wave & 3;

    // XCD-aware swizzle (all grids are multiples of 8)
    int nx = N >> 8;
    int nwg = nx * (M / BM);
    int bid = blockIdx.x;
    int wg = (bid & 7) * (nwg >> 3) + (bid >> 3);
    int m0 = (wg / nx) * BM, n0 = (wg % nx) << 8;

    const short* Atile = A + (size_t)m0 * K;
    const short* Btile = Bt + (size_t)n0 * K;
    const int NT = K >> 6;

    auto stageA = [&](int t, int kh, int buf) {
        int tw = (t >= NT) ? t - NT : t;
        const short* g = Atile + tw * 64 + kh * 32;
        short* dst = ldsA[buf][kh];
        #pragma unroll
        for (int s = 0; s < LA; s++) {
            int n = wave * (64 * LA) + s * 64 + lane;
            int row = n >> 2, c = n & 3;
            int cs = (c ^ (row & 3) ^ ((row >> 2) & 3)) & 3;
            gload_lds16(g + (size_t)row * K + cs * 8, (char*)dst + n * 16);
        }
    };
    auto stageB = [&](int t, int kh, int buf) {
        int tw = (t >= NT) ? t - NT : t;
        const short* g = Btile + tw * 64 + kh * 32;
        short* dst = ldsB[buf][kh];
        #pragma unroll
        for (int s = 0; s < 2; s++) {
            int n = wave * 128 + s * 64 + lane;
            int row = n >> 2, c = n & 3;
            int cs = (c ^ (row & 3) ^ ((row >> 2) & 3)) & 3;
            gload_lds16(g + (size_t)row * K + cs * 8, (char*)dst + n * 16);
        }
    };

    f32x4 acc[MFR][4] = {};
    bf16x8 bv[4];

    // prologue: T0 fully + T1.kh0; retire T0, keep T1.kh0 in flight
    stageA(0, 0, 0); stageB(0, 0, 0);
    stageA(0, 1, 0); stageB(0, 1, 0);
    stageA(1, 0, 1); stageB(1, 0, 1);
    CKV();
    __builtin_amdgcn_s_barrier();
    __builtin_amdgcn_sched_barrier(0);

    const int NITER = NT >> 1;
    for (int j = 0; j < NITER; j++) {
        int T = 2 * j;
        GPH(0, 0, 0, true,  stageA(T+1, 1, 1), NOCK);
        GPH(0, 0, 1, false, stageB(T+1, 1, 1), NOCK);
        GPH(0, 1, 0, true,  stageA(T+2, 0, 0), NOCK);
        GPH(0, 1, 1, false, stageB(T+2, 0, 0), CKV());
        GPH(1, 0, 0, true,  stageA(T+2, 1, 0), NOCK);
        GPH(1, 0, 1, false, stageB(T+2, 1, 0), NOCK);
        GPH(1, 1, 0, true,  stageA(T+3, 0, 1), NOCK);
        GPH(1, 1, 1, false, stageB(T+3, 0, 1), CKV());
    }
    // drain wrapped prefetches so no LDS writes outlive the block
    asm volatile("s_waitcnt vmcnt(0)" ::: "memory");
    __builtin_amdgcn_s_barrier();

    #pragma unroll
    for (int n = 0; n < 4; n++) {
        int colb = n0 + wn * 64 + n * 16 + lm;
        float bvs = BIAS ? bias[colb] : 0.f;
        #pragma unroll
        for (int m = 0; m < MFR; m++) {
            #pragma unroll
            for (int r = 0; r < 4; r++) {
                int row = m0 + wm * (BM/2) + m * 16 + l4 * 4 + r;
                float v = acc[m][n][r] + bvs;
                if (GELU) v = 0.5f * v * (1.0f + erff(v * 0.70710678118654752f));
                size_t off = (size_t)row * N + colb;
                if (RES) v += res[off];
                if (OUTBF16) ((short*)Cout)[off] = (short)f2bf(v);
                else         ((float*)Cout)[off] = v;
            }
        }
    }
}

// ---------------- MFMA flash attention (read-side XOR-swizzled LDS) ----------------
__global__ __launch_bounds__(256) void attn_kernel(
        const short* __restrict__ qkv, const short* __restrict__ vT,
        const float* __restrict__ mask, short* __restrict__ ctx) {
    __shared__ __align__(16) short Ks[64*128];   // [kv][d], chunk-swizzled
    __shared__ __align__(16) short Vt[128*64];   // [d][kv], chunk-swizzled
    __shared__ __align__(16) short Ps[4][16*72]; // per-wave P, pitch 72
    int t = threadIdx.x;
    int wave = t >> 6, lane = t & 63;
    int l4 = lane >> 4, lm = lane & 15;
    int q0 = blockIdx.x * 64, h = blockIdx.y, zb = blockIdx.z;
    const float scale = 0.08838834764831845f;  // 1/sqrt(128)

    bf16x8 aq[4];
    {
        const short* qrow = qkv + (size_t)(zb*S_ + q0 + wave*16 + lm) * LDQ + h*DH_;
        #pragma unroll
        for (int ks = 0; ks < 4; ks++)
            aq[ks] = *(const bf16x8*)(qrow + ks*32 + l4*8);
    }

    float m_r[4], l_r[4];
    #pragma unroll
    for (int r = 0; r < 4; r++) { m_r[r] = -INFINITY; l_r[r] = 0.f; }
    f32x4 o[8];
    #pragma unroll
    for (int i = 0; i < 8; i++) o[i] = (f32x4){0.f, 0.f, 0.f, 0.f};

    for (int kv0 = 0; kv0 < S_; kv0 += 64) {
        __syncthreads();
        #pragma unroll
        for (int L = 0; L < 4; L++) {
            int c = (wave*4 + L)*64 + lane;
            int krow = c >> 4, kc = c & 15;
            int ksrc = (kc & 8) | ((kc ^ (krow & 7)) & 7);
            gload_lds16(qkv + (size_t)(zb*S_ + kv0 + krow)*LDQ + 2048 + h*DH_ + ksrc*8,
                        (char*)Ks + c*16);
            int drow = c >> 3, dc = c & 7;
            int dsrc = dc ^ (drow & 7);
            gload_lds16(vT + ((size_t)(h*DH_ + drow)*2 + zb)*S_ + kv0 + dsrc*8,
                        (char*)Vt + c*16);
        }
        __syncthreads();

        f32x4 s[4];
        #pragma unroll
        for (int nb = 0; nb < 4; nb++) s[nb] = (f32x4){0.f, 0.f, 0.f, 0.f};
        __builtin_amdgcn_s_setprio(1);
        #pragma unroll
        for (int nb = 0; nb < 4; nb++) {
            int row = nb*16 + lm;
            #pragma unroll
            for (int ks = 0; ks < 4; ks++) {
                bf16x8 bk = *(const bf16x8*)((const char*)Ks +
                              ((row*256 + ks*64 + l4*16) ^ ((row & 7) << 4)));
                s[nb] = __builtin_amdgcn_mfma_f32_16x16x32_bf16(aq[ks], bk, s[nb], 0, 0, 0);
            }
        }
        __builtin_amdgcn_s_setprio(0);

        float mk[4];
        #pragma unroll
        for (int nb = 0; nb < 4; nb++) mk[nb] = mask[(size_t)zb*S_ + kv0 + nb*16 + lm];

        float pv_[4][4], fac[4];
        #pragma unroll
        for (int r = 0; r < 4; r++) {
            float vmax = -INFINITY;
            #pragma unroll
            for (int nb = 0; nb < 4; nb++) {
                float v = s[nb][r] * scale + mk[nb];
                pv_[r][nb] = v;
                vmax = fmaxf(vmax, v);
            }
            vmax = fmaxf(vmax, __shfl_xor(vmax, 1, 64));
            vmax = fmaxf(vmax, __shfl_xor(vmax, 2, 64));
            vmax = fmaxf(vmax, __shfl_xor(vmax, 4, 64));
            vmax = fmaxf(vmax, __shfl_xor(vmax, 8, 64));
            float nm = fmaxf(m_r[r], vmax);
            fac[r] = __expf(m_r[r] - nm);
            float ps = 0.f;
            #pragma unroll
            for (int nb = 0; nb < 4; nb++) {
                float e = __expf(pv_[r][nb] - nm);
                pv_[r][nb] = e;
                ps += e;
            }
            ps += __shfl_xor(ps, 1, 64);
            ps += __shfl_xor(ps, 2, 64);
            ps += __shfl_xor(ps, 4, 64);
            ps += __shfl_xor(ps, 8, 64);
            l_r[r] = l_r[r] * fac[r] + ps;
            m_r[r] = nm;
        }
        #pragma unroll
        for (int i = 0; i < 8; i++)
            #pragma unroll
            for (int r = 0; r < 4; r++) o[i][r] *= fac[r];

        short* Pw = (short*)Ps[wave];
        #pragma unroll
        for (int r = 0; r < 4; r++)
            #pragma unroll
            for (int nb = 0; nb < 4; nb++)
                Pw[(l4*4 + r)*72 + nb*16 + lm] = (short)f2bf(pv_[r][nb]);

        __builtin_amdgcn_s_setprio(1);
        #pragma unroll
        for (int ks = 0; ks < 2; ks++) {
            bf16x8 ap = *(const bf16x8*)(Pw + lm*72 + ks*32 + l4*8);
            #pragma unroll
            for (int nd = 0; nd < 8; nd++) {
                int d = nd*16 + lm;
                bf16x8 bvv = *(const bf16x8*)((const char*)Vt +
                              (((d*128) + ks*64 + l4*16) ^ ((d & 7) << 4)));
                o[nd] = __builtin_amdgcn_mfma_f32_16x16x32_bf16(ap, bvv, o[nd], 0, 0, 0);
            }
        }
        __builtin_amdgcn_s_setprio(0);
    }

    float inv[4];
    #pragma unroll
    for (int r = 0; r < 4; r++) inv[r] = 1.0f / l_r[r];
    #pragma unroll
    for (int nd = 0; nd < 8; nd++) {
        #pragma unroll
        for (int r = 0; r < 4; r++) {
            size_t row = (size_t)(zb*S_ + q0 + wave*16 + l4*4 + r);
            ctx[row * HD + h*DH_ + nd*16 + lm] = (short)f2bf(o[nd][r] * inv[r]);
        }
    }
}

extern "C" void kernel_launch(void* const* d_in, const int* in_sizes, int n_in,
                              void* d_out, int out_size, void* d_ws, size_t ws_size,
                              hipStream_t stream) {
    const float* x      = (const float*)d_in[0];
    const float* mask   = (const float*)d_in[1];
    const float* ln1_g  = (const float*)d_in[2];
    const float* ln1_b  = (const float*)d_in[3];
    const float* ln2_g  = (const float*)d_in[4];
    const float* ln2_b  = (const float*)d_in[5];
    const float* Wq     = (const float*)d_in[6];
    const float* Wk     = (const float*)d_in[7];
    const float* Wv     = (const float*)d_in[8];
    const float* Wo     = (const float*)d_in[9];
    const float* W1     = (const float*)d_in[10];
    const float* b1     = (const float*)d_in[11];
    const float* W2     = (const float*)d_in[12];
    const float* b2     = (const float*)d_in[13];
    float* out = (float*)d_out;

    char* ws = (char*)d_ws;
    size_t off = 0;
    const size_t WSQ  = (size_t)HD * HD * 2;        // 8 MiB
    const size_t WFF  = (size_t)HD * FF_ * 2;       // 32 MiB
    const size_t ACTB = (size_t)MROWS * HD * 2;     // 16 MiB
    short* WqkvT = (short*)(ws + off); off += 3 * WSQ;             // 24 MiB
    short* WoT   = (short*)(ws + off); off += WSQ;                 // 8
    short* W1T   = (short*)(ws + off); off += WFF;                 // 32
    short* W2T   = (short*)(ws + off); off += WFF;                 // 32
    short* hb    = (short*)(ws + off); off += ACTB;                // 16
    short* qkv   = (short*)(ws + off); off += (size_t)MROWS * LDQ * 2;  // 48
    short* vTb   = (short*)(ws + off); off += (size_t)HD * B_ * S_ * 2; // 16
    float* x1    = (float*)(ws + off); off += (size_t)MROWS * HD * 4;   // 32  (total 208 MiB)
    short* cb    = WqkvT;   // overlay: ctx over dead WqkvT
    short* act   = qkv;     // overlay: act (64 MiB) over dead qkv+vT

    dim3 blk(256);

    trcvt_kernel<<<dim3(HD/32,  HD/32),  blk, 0, stream>>>(Wq, WqkvT,                 HD, HD);
    trcvt_kernel<<<dim3(HD/32,  HD/32),  blk, 0, stream>>>(Wk, WqkvT + (size_t)HD*HD, HD, HD);
    trcvt_kernel<<<dim3(HD/32,  HD/32),  blk, 0, stream>>>(Wv, WqkvT + (size_t)2*HD*HD, HD, HD);
    trcvt_kernel<<<dim3(HD/32,  HD/32),  blk, 0, stream>>>(Wo, WoT, HD, HD);
    trcvt_kernel<<<dim3(FF_/32, HD/32),  blk, 0, stream>>>(W1, W1T, HD, FF_);
    trcvt_kernel<<<dim3(HD/32,  FF_/32), blk, 0, stream>>>(W2, W2T, FF_, HD);

    // 1) h = LN1(x) -> bf16
    ln_kernel<<<MROWS, blk, 0, stream>>>(x, ln1_g, ln1_b, hb);

    // 2) qkv = h @ [Wq|Wk|Wv]  (fused, N=6144); 384 blocks
    gemm256<256,true,false,false,false><<<dim3((MROWS/256)*(LDQ/256)), 512, 0, stream>>>(
        hb, WqkvT, nullptr, nullptr, qkv, MROWS, LDQ, HD);

    // 2.5) vT[hd][b][s] = qkv v-part transposed
    vtrans_kernel<<<dim3(HD/32, S_/32, B_), blk, 0, stream>>>(qkv, vTb);

    // 3) ctx = softmax(qk^T*scale + mask) v  -> bf16 (over WqkvT)
    attn_kernel<<<dim3(S_/64, NH_, B_), blk, 0, stream>>>(qkv, vTb, mask, cb);

    // 4) x1 = x + ctx @ Wo  (f32); BM=128 -> 256 blocks (full machine)
    gemm256<128,false,false,true,false><<<dim3((MROWS/128)*(HD/256)), 512, 0, stream>>>(
        cb, WoT, nullptr, x, x1, MROWS, HD, HD);

    // 5) h2 = LN2(x1) -> bf16 (reuse hb)
    ln_kernel<<<MROWS, blk, 0, stream>>>(x1, ln2_g, ln2_b, hb);

    // 6) act = gelu(h2 @ W1 + b1) -> bf16 (overlays qkv+vT); 512 blocks
    gemm256<256,true,true,false,true><<<dim3((MROWS/256)*(FF_/256)), 512, 0, stream>>>(
        hb, W1T, b1, nullptr, act, MROWS, FF_, HD);

    // 7) out = x1 + act @ W2 + b2  (f32); BM=128 -> 256 blocks
    gemm256<128,false,true,true,false><<<dim3((MROWS/128)*(HD/256)), 512, 0, stream>>>(
        act, W2T, b2, x1, out, MROWS, HD, FF_);
}